// Round 3
// 240.105 us; speedup vs baseline: 1.2157x; 1.2157x over previous
//
#include <hip/hip_runtime.h>
#include <math.h>

// Problem constants
#define Bq 2
#define Sq 2048
#define Cq 768
#define Hq 12
#define Dq 64

#define PANEL_SHORTS 196608   // 24 steps x 8192 shorts (128 rows x [hi32|lo32])
#define PANELS_X  32
#define PANELS_WQ 18
#define PANELS_WP 6

typedef __bf16 bfv8 __attribute__((ext_vector_type(8)));
typedef _Float16 f16x8 __attribute__((ext_vector_type(8)));
typedef __fp16 fp16v2 __attribute__((ext_vector_type(2)));   // cvt_pkrtz result type
typedef float f32x4 __attribute__((ext_vector_type(4)));
#define MFMA16(a, b, c)  __builtin_amdgcn_mfma_f32_16x16x32_bf16(a, b, c, 0, 0, 0)
#define MFMA16F(a, b, c) __builtin_amdgcn_mfma_f32_16x16x32_f16(a, b, c, 0, 0, 0)

// fold head-scale 1/8 and log2(e) into q so attention runs in log2 domain
#define SCALEQ 0.18033688011112042f

static __device__ inline unsigned short bfbits(float x) {
    __bf16 b = (__bf16)x;
    return __builtin_bit_cast(unsigned short, b);
}
static __device__ inline float bf2f(unsigned short b) {
    return (float)__builtin_bit_cast(__bf16, b);
}
static __device__ inline unsigned short lobits(float x, unsigned short hb) {
    return bfbits(x - bf2f(hb));
}
static __device__ inline unsigned short f16bits(float x) {
    _Float16 h = (_Float16)x;
    return __builtin_bit_cast(unsigned short, h);
}
static __device__ inline unsigned int pk16(float a, float b) {
    fp16v2 h = __builtin_amdgcn_cvt_pkrtz(a, b);
    return __builtin_bit_cast(unsigned int, h);
}

// async 16B global->LDS copy; lds dest is wave-uniform base (+lane*16 by HW)
static __device__ inline void gld_lds16(const unsigned short* g, unsigned short* l) {
    __builtin_amdgcn_global_load_lds(
        (const __attribute__((address_space(1))) unsigned int*)g,
        (__attribute__((address_space(3))) unsigned int*)l, 16, 0, 0);
}

// ---------------------------------------------------------------------------
// Kernel 0: RoPE cos/sin tables  [S][32] each, fp64-accurate
// ---------------------------------------------------------------------------
__global__ void freq_kernel(float* __restrict__ ctab, float* __restrict__ stab) {
    int idx = blockIdx.x * blockDim.x + threadIdx.x;   // 0..65535
    int s = idx >> 5;
    int i = idx & 31;
    double f = (double)s * exp(-(double)i * 0.28782313662425573); // ln(1e4)/32
    ctab[idx] = (float)cos(f);
    stab[idx] = (float)sin(f);
}

// ---------------------------------------------------------------------------
// Kernel 1: fp32 -> bf16 hi/lo split into GEMM panel-blocked, PRE-SWIZZLED
// layout (unchanged; GEMM inputs stay 3-term bf16 for fp32-grade accuracy).
// ---------------------------------------------------------------------------
__global__ __launch_bounds__(256) void split_kernel(
    const float* __restrict__ x, const float* __restrict__ wq,
    const float* __restrict__ wp,
    unsigned short* __restrict__ xs, unsigned short* __restrict__ wqs,
    unsigned short* __restrict__ wps)
{
    const int cid  = blockIdx.x * 256 + threadIdx.x;  // 16B output chunk id
    const int panel = cid / 24576;                    // PANEL_SHORTS/8
    const int pos8  = cid % 24576;
    const int step = pos8 >> 10;
    const int rem  = pos8 & 1023;
    const int J    = rem >> 6;
    const int lane = rem & 63;
    const int rowp = J * 8 + (lane >> 3);
    const int lc   = (lane & 7) ^ (rowp & 7);
    const int k    = step * 32 + (lc & 3) * 8;
    const int islo = lc >> 2;
    const float* src; unsigned short* dst; int prow;
    if (panel < PANELS_X) {
        src = x;  dst = xs;  prow = panel;
    } else if (panel < PANELS_X + PANELS_WQ) {
        src = wq; dst = wqs; prow = panel - PANELS_X;
    } else {
        src = wp; dst = wps; prow = panel - PANELS_X - PANELS_WQ;
    }
    const int row = prow * 128 + rowp;
    float4 v0 = *(const float4*)(src + (size_t)row * Cq + k);
    float4 v1 = *(const float4*)(src + (size_t)row * Cq + k + 4);
    float vf[8] = {v0.x, v0.y, v0.z, v0.w, v1.x, v1.y, v1.z, v1.w};
    unsigned short o[8];
    #pragma unroll
    for (int j = 0; j < 8; ++j) {
        unsigned short h = bfbits(vf[j]);
        o[j] = islo ? lobits(vf[j], h) : h;
    }
    *(uint4*)&dst[(size_t)prow * PANEL_SHORTS + (size_t)pos8 * 8] = *(uint4*)o;
}

// ---------------------------------------------------------------------------
// MFMA NT GEMM on panel-blocked pre-swizzled inputs. 128x128 tile, BK=32,
// 4 waves 2x2, 4x4 acc/wave, 3-term split. Staging = identity global_load_lds.
// MODE 0: QKV + RoPE epilogue -> SINGLE fp16 images for attention:
//   q -> [bh][s][64] fp16, pre-scaled by 0.125*log2e
//   k -> blocked tile image [bh][kt][key(64) x d-chunks swizzled] fp16
//   v -> blocked tile image [bh][kt][d(64) x key-chunks swizzled] fp16
// MODE 1: proj + bias -> fp32 [M][768].
// ---------------------------------------------------------------------------
template <int MODE>
__global__ __launch_bounds__(256) void gemm_mfma_kernel(
    const unsigned short* __restrict__ Apr, const unsigned short* __restrict__ Bpr,
    const float* __restrict__ ctab, const float* __restrict__ stab,
    unsigned short* __restrict__ qp, unsigned short* __restrict__ kp,
    unsigned short* __restrict__ vp,
    float* __restrict__ out0, const float* __restrict__ bias)
{
    __shared__ unsigned short sA[128 * 64];
    __shared__ unsigned short sB[128 * 64];

    const int t    = threadIdx.x;
    const int w    = t >> 6;
    const int lane = t & 63;
    const int ml   = lane & 15;
    const int quad = lane >> 4;
    const int wm   = w >> 1;
    const int wn   = w & 1;

    const int mBase = blockIdx.y * 128;
    const int nBase = blockIdx.x * 128;

    const bool isB = (w >= 2);
    const unsigned short* gpan = (isB ? Bpr : Apr)
        + (size_t)((isB ? nBase : mBase) >> 7) * PANEL_SHORTS;
    unsigned short* sdst = isB ? sB : sA;
    const int wl = w & 1;
    const int Jb = wl * 8;

    f32x4 acc[4][4];
    #pragma unroll
    for (int mi = 0; mi < 4; ++mi)
        #pragma unroll
        for (int ni = 0; ni < 4; ++ni)
            acc[mi][ni] = (f32x4){0.f, 0.f, 0.f, 0.f};

    for (int k0 = 0; k0 < Cq; k0 += 32) {
        const unsigned short* gt = gpan + (k0 >> 5) * 8192;
        __syncthreads();
        #pragma unroll
        for (int j = 0; j < 8; ++j)
            gld_lds16(gt + (Jb + j) * 512 + lane * 8, sdst + (Jb + j) * 512);
        __syncthreads();

        bfv8 aFh[4], aFl[4], bFh[4], bFl[4];
        #pragma unroll
        for (int mi = 0; mi < 4; ++mi) {
            const int row = wm * 64 + mi * 16 + ml;
            aFh[mi] = *(const bfv8*)&sA[row * 64 + ((quad ^ (row & 7)) << 3)];
            aFl[mi] = *(const bfv8*)&sA[row * 64 + (((4 + quad) ^ (row & 7)) << 3)];
        }
        #pragma unroll
        for (int ni = 0; ni < 4; ++ni) {
            const int row = wn * 64 + ni * 16 + ml;
            bFh[ni] = *(const bfv8*)&sB[row * 64 + ((quad ^ (row & 7)) << 3)];
            bFl[ni] = *(const bfv8*)&sB[row * 64 + (((4 + quad) ^ (row & 7)) << 3)];
        }
        #pragma unroll
        for (int mi = 0; mi < 4; ++mi)
            #pragma unroll
            for (int ni = 0; ni < 4; ++ni) {
                acc[mi][ni] = MFMA16(aFh[mi], bFh[ni], acc[mi][ni]);
                acc[mi][ni] = MFMA16(aFl[mi], bFh[ni], acc[mi][ni]);
                acc[mi][ni] = MFMA16(aFh[mi], bFl[ni], acc[mi][ni]);
            }
    }

    // ---- epilogue (C-layout: row = quad*4 + r, col = ml) ----
    if (MODE == 0) {
        const int which = nBase / Cq;   // 0=q 1=k 2=v
        #pragma unroll
        for (int mi = 0; mi < 4; ++mi) {
            const int gm = mBase + wm * 64 + mi * 16 + quad * 4;  // + r
            const int bb = gm >> 11;
            const int s0 = gm & 2047;
            #pragma unroll
            for (int ni = 0; ni < 4; ++ni) {
                const int gn = nBase + wn * 64 + ni * 16 + ml;
                const int c  = gn - which * Cq;
                const int hh = c >> 6;
                const int dd = c & 63;
                const size_t hb = (size_t)(bb * Hq + hh);
                if (which < 2) {
                    #pragma unroll
                    for (int r = 0; r < 4; ++r) {
                        float val = acc[mi][ni][r];
                        float pv  = __shfl_xor(val, 1, 64);   // d-pair partner
                        const int fi = (s0 + r) * 32 + (dd >> 1);
                        float c0 = ctab[fi], sn = stab[fi];
                        float o = (dd & 1) ? (val * c0 + pv * sn)
                                           : (val * c0 - pv * sn);
                        if (which == 0) {
                            o *= SCALEQ;                      // 1/8 * log2(e)
                            qp[(hb * Sq + s0 + r) * 64 + dd] = f16bits(o);
                        } else {
                            const int ss = s0 + r, rr = ss & 63, kt2 = ss >> 6;
                            kp[(hb * 32 + kt2) * 4096 + rr * 64
                               + (((dd >> 3) ^ (rr & 7)) << 3) + (dd & 7)] = f16bits(o);
                        }
                    }
                } else {
                    // V tile image: row = d, key chunks swizzled by (d&7)
                    unsigned short hv[4];
                    #pragma unroll
                    for (int r = 0; r < 4; ++r)
                        hv[r] = f16bits(acc[mi][ni][r]);
                    const int kt2 = s0 >> 6;
                    *(ushort4*)&vp[(hb * 32 + kt2) * 4096 + dd * 64
                        + ((((s0 & 63) >> 3) ^ (dd & 7)) << 3) + (s0 & 7)]
                        = *(ushort4*)hv;
                }
            }
        }
    } else {
        #pragma unroll
        for (int mi = 0; mi < 4; ++mi) {
            const int gm = mBase + wm * 64 + mi * 16 + quad * 4;
            #pragma unroll
            for (int ni = 0; ni < 4; ++ni) {
                const int gn = nBase + wn * 64 + ni * 16 + ml;
                const float bz = bias[gn];
                #pragma unroll
                for (int r = 0; r < 4; ++r)
                    out0[(size_t)(gm + r) * Cq + gn] = acc[mi][ni][r] + bz;
            }
        }
    }
}

// ---------------------------------------------------------------------------
// Kernel 2: fp16 single-term MFMA flash attention, SWAPPED operands.
// Grid 768 = 32 qt x 24 bh (XCD = bh%8).
// S^T = mfma(K, Q): lane owns ONE q-column (q = ml); keys = ng*16+quad*4+r.
// Softmax in log2 domain: in-lane max/sum + shfl_xor(16/32); defer-max skip.
// P -> fp16 via v_cvt_pkrtz, transposed through tiny stride-72 LDS buffer.
// pbuf write/read both stay in the unsigned-int TBAA family (uint2 store,
// uint4 load + bit_cast) so the same-wave LDS round-trip cannot be reordered.
// O^T = mfma(V^T, P^T); epilogue transposes via LDS (reusing K/V space) so
// attns panel-image writes stay coalesced and identical to before.
// LDS: 8KB K + 8KB V + 9KB pbuf = 25.6KB.
// ---------------------------------------------------------------------------
__global__ __launch_bounds__(256, 4) void attn_mfma_kernel(
    const unsigned short* __restrict__ qp, const unsigned short* __restrict__ kp,
    const unsigned short* __restrict__ vp, unsigned short* __restrict__ attns)
{
    __shared__ __align__(16) unsigned short smem[12800];
    unsigned short* k_s = smem;          // [64 keys][8 d-chunks swz] fp16
    unsigned short* v_s = smem + 4096;   // [64 d][8 key-chunks swz] fp16
    unsigned short* pb  = smem + 8192;   // [64 q-rows][72] fp16 P (stride 72)

    const int t    = threadIdx.x;
    const int w    = t >> 6;
    const int lane = t & 63;
    const int ml   = lane & 15;
    const int quad = lane >> 4;
    const int bi   = blockIdx.x;
    const int bh   = bi % 24;               // XCD = bh % 8
    const int qt   = bi / 24;               // 0..31

    // staging: waves 0,1 -> K; waves 2,3 -> V; 4KB (4 chunks) per wave
    const bool isV = (w >= 2);
    const unsigned short* gsrc = isV ? vp : kp;
    unsigned short* sdst = isV ? v_s : k_s;
    const int Jb = (w & 1) * 4;
    const size_t gb = (size_t)bh * 131072;  // 32 tiles x 4096 shorts

    // ---- Q B-frag (fp16), q-row = qt*64 + w*16 + ml, col(ml) <-> q ----
    const size_t qrow = ((size_t)bh * Sq + qt * 64 + w * 16 + ml) * 64;
    f16x8 bQ[2];
    bQ[0] = *(const f16x8*)(qp + qrow + quad * 8);
    bQ[1] = *(const f16x8*)(qp + qrow + 32 + quad * 8);

    float m_st = -INFINITY, l_st = 0.f;
    f32x4 O[4];
    #pragma unroll
    for (int ng = 0; ng < 4; ++ng) O[ng] = (f32x4){0.f, 0.f, 0.f, 0.f};

    unsigned short* pbl = pb + (w * 16 + ml) * 72;   // this lane's q-row

    for (int kt = 0; kt < 32; ++kt) {
        __syncthreads();
        {
            const unsigned short* gt = gsrc + gb + (size_t)kt * 4096;
            #pragma unroll
            for (int j = 0; j < 4; ++j)
                gld_lds16(gt + (Jb + j) * 512 + lane * 8, sdst + (Jb + j) * 512);
        }
        __syncthreads();

        // ---- S^T = K x Q (keys x q), 1-term fp16, log2 domain ----
        f32x4 S[4];
        #pragma unroll
        for (int ng = 0; ng < 4; ++ng) {
            const int row = ng * 16 + ml;            // key row (A supply)
            f32x4 acc = (f32x4){0.f, 0.f, 0.f, 0.f};
            #pragma unroll
            for (int ks = 0; ks < 2; ++ks) {
                f16x8 aK = *(const f16x8*)
                    &k_s[row * 64 + (((ks * 4 + quad) ^ (row & 7)) << 3)];
                acc = MFMA16F(aK, bQ[ks], acc);
            }
            S[ng] = acc;
        }

        // ---- online softmax for q = ml: 16 in-lane keys + cross-quad ----
        float a0 = fmaxf(fmaxf(S[0][0], S[0][1]), fmaxf(S[0][2], S[0][3]));
        float a1 = fmaxf(fmaxf(S[1][0], S[1][1]), fmaxf(S[1][2], S[1][3]));
        float a2 = fmaxf(fmaxf(S[2][0], S[2][1]), fmaxf(S[2][2], S[2][3]));
        float a3 = fmaxf(fmaxf(S[3][0], S[3][1]), fmaxf(S[3][2], S[3][3]));
        float mx = fmaxf(fmaxf(a0, a1), fmaxf(a2, a3));
        mx = fmaxf(mx, __shfl_xor(mx, 16, 64));
        mx = fmaxf(mx, __shfl_xor(mx, 32, 64));
        // defer-max: rescale only if tile max outgrew running max by >11 (log2)
        if (__any(mx > m_st + 11.f)) {
            float nm = fmaxf(m_st, mx);
            float al = exp2f(m_st - nm);
            #pragma unroll
            for (int ng = 0; ng < 4; ++ng) O[ng] = O[ng] * al;
            l_st *= al;
            m_st = nm;
        }

        // ---- p = exp2(S - m) -> fp16 pack -> pbuf row (keys in order) ----
        float ps = 0.f;
        #pragma unroll
        for (int ng = 0; ng < 4; ++ng) {
            float p0 = exp2f(S[ng][0] - m_st);
            float p1 = exp2f(S[ng][1] - m_st);
            float p2 = exp2f(S[ng][2] - m_st);
            float p3 = exp2f(S[ng][3] - m_st);
            ps += (p0 + p1) + (p2 + p3);
            uint2 u;
            u.x = pk16(p0, p1);
            u.y = pk16(p2, p3);
            *(uint2*)&pbl[ng * 16 + quad * 4] = u;   // keys ng*16+quad*4..+3
        }
        ps += __shfl_xor(ps, 16, 64);
        ps += __shfl_xor(ps, 32, 64);
        l_st += ps;

        // ---- O^T += V^T x P^T ----
        #pragma unroll
        for (int ks = 0; ks < 2; ++ks) {
            uint4 pu = *(const uint4*)&pbl[ks * 32 + quad * 8];
            f16x8 bP = __builtin_bit_cast(f16x8, pu);
            #pragma unroll
            for (int ngd = 0; ngd < 4; ++ngd) {
                const int row = ngd * 16 + ml;       // d row (A supply)
                f16x8 aV = *(const f16x8*)
                    &v_s[row * 64 + (((ks * 4 + quad) ^ (row & 7)) << 3)];
                O[ngd] = MFMA16F(aV, bP, O[ngd]);
            }
        }
    }

    // ---- epilogue: O^T/l -> LDS transpose -> panel-blocked hi/lo image ----
    __syncthreads();                         // all PV reads done; reuse smem
    float* obuf = (float*)smem;              // [64 q-rows][68] f32
    {
        const float il = 1.0f / l_st;
        float* obl = obuf + (w * 16 + ml) * 68;
        #pragma unroll
        for (int ngd = 0; ngd < 4; ++ngd) {
            f32x4 ov = O[ngd] * il;          // d = ngd*16 + quad*4 + r
            *(f32x4*)&obl[ngd * 16 + quad * 4] = ov;
        }
    }
    __syncthreads();
    const int bb = bh / Hq, hh = bh % Hq;
    #pragma unroll
    for (int r = 0; r < 4; ++r) {
        const int srow = qt * 64 + w * 16 + quad * 4 + r;
        const int mrow = bb * 2048 + srow;
        const int panel = mrow >> 7, r128 = mrow & 127;
        const size_t rbase = (size_t)panel * PANEL_SHORTS
                           + (r128 >> 3) * 512 + (r128 & 7) * 64;
        #pragma unroll
        for (int ng = 0; ng < 4; ++ng) {
            const int k = hh * 64 + ng * 16 + ml;
            float o = obuf[(w * 16 + quad * 4 + r) * 68 + ng * 16 + ml];
            unsigned short h0 = bfbits(o);
            unsigned short l0 = lobits(o, h0);
            const int step = k >> 5;
            const int lch  = (k & 31) >> 3;
            const size_t sb = rbase + (size_t)step * 8192;
            attns[sb + ((lch ^ (r128 & 7)) << 3)       + (k & 7)] = h0;
            attns[sb + (((4 + lch) ^ (r128 & 7)) << 3) + (k & 7)] = l0;
        }
    }
}

// ---------------------------------------------------------------------------
extern "C" void kernel_launch(void* const* d_in, const int* in_sizes, int n_in,
                              void* d_out, int out_size, void* d_ws, size_t ws_size,
                              hipStream_t stream) {
    const float* x     = (const float*)d_in[0];
    const float* Wqkv  = (const float*)d_in[1];
    const float* Wproj = (const float*)d_in[2];
    const float* bproj = (const float*)d_in[3];
    float* out = (float*)d_out;

    char* p = (char*)d_ws;
    unsigned short* xs    = (unsigned short*)p; p += (size_t)PANELS_X  * PANEL_SHORTS * 2;
    unsigned short* wqs   = (unsigned short*)p; p += (size_t)PANELS_WQ * PANEL_SHORTS * 2;
    unsigned short* wps   = (unsigned short*)p; p += (size_t)PANELS_WP * PANEL_SHORTS * 2;
    unsigned short* qp    = (unsigned short*)p; p += (size_t)24 * Sq * 64 * 2;      // fp16
    unsigned short* kp    = (unsigned short*)p; p += (size_t)24 * 131072 * 2;       // fp16
    unsigned short* vp    = (unsigned short*)p; p += (size_t)24 * 131072 * 2;       // fp16
    unsigned short* attns = (unsigned short*)p; p += (size_t)PANELS_X * PANEL_SHORTS * 2;
    float* ctab = (float*)p; p += (size_t)Sq * 32 * 4;
    float* stab = (float*)p; p += (size_t)Sq * 32 * 4;

    freq_kernel<<<256, 256, 0, stream>>>(ctab, stab);
    split_kernel<<<(PANELS_X + PANELS_WQ + PANELS_WP) * 24576 / 256, 256, 0, stream>>>(
        x, Wqkv, Wproj, xs, wqs, wps);
    gemm_mfma_kernel<0><<<dim3(18, 32), 256, 0, stream>>>(
        xs, wqs, ctab, stab, qp, kp, vp, nullptr, nullptr);
    attn_mfma_kernel<<<dim3(32 * 24), 256, 0, stream>>>(qp, kp, vp, attns);
    gemm_mfma_kernel<1><<<dim3(6, 32), 256, 0, stream>>>(
        attns, wps, ctab, stab, nullptr, nullptr, nullptr, out, bproj);
}

// Round 5
// 223.921 us; speedup vs baseline: 1.3035x; 1.0723x over previous
//
#include <hip/hip_runtime.h>
#include <math.h>

// Problem constants
#define Bq 2
#define Sq 2048
#define Cq 768
#define Hq 12
#define Dq 64

#define PANEL_SHORTS 196608   // 24 steps x 8192 shorts (128 rows x [hi32|lo32])
#define PANELS_X  32
#define PANELS_WQ 18
#define PANELS_WP 6

typedef __bf16 bfv8 __attribute__((ext_vector_type(8)));
typedef _Float16 f16x8 __attribute__((ext_vector_type(8)));
typedef __fp16 fp16v2 __attribute__((ext_vector_type(2)));   // cvt_pkrtz result type
typedef float f32x4 __attribute__((ext_vector_type(4)));
#define MFMA16(a, b, c)  __builtin_amdgcn_mfma_f32_16x16x32_bf16(a, b, c, 0, 0, 0)
#define MFMA16F(a, b, c) __builtin_amdgcn_mfma_f32_16x16x32_f16(a, b, c, 0, 0, 0)

// fold head-scale 1/8 and log2(e) into q so attention runs in log2 domain
#define SCALEQ 0.18033688011112042f

static __device__ inline unsigned short bfbits(float x) {
    __bf16 b = (__bf16)x;
    return __builtin_bit_cast(unsigned short, b);
}
static __device__ inline float bf2f(unsigned short b) {
    return (float)__builtin_bit_cast(__bf16, b);
}
static __device__ inline unsigned short lobits(float x, unsigned short hb) {
    return bfbits(x - bf2f(hb));
}
static __device__ inline unsigned short f16bits(float x) {
    _Float16 h = (_Float16)x;
    return __builtin_bit_cast(unsigned short, h);
}
static __device__ inline unsigned int pk16(float a, float b) {
    fp16v2 h = __builtin_amdgcn_cvt_pkrtz(a, b);
    return __builtin_bit_cast(unsigned int, h);
}

// async 16B global->LDS copy; lds dest is wave-uniform base (+lane*16 by HW)
static __device__ inline void gld_lds16(const unsigned short* g, unsigned short* l) {
    __builtin_amdgcn_global_load_lds(
        (const __attribute__((address_space(1))) unsigned int*)g,
        (__attribute__((address_space(3))) unsigned int*)l, 16, 0, 0);
}

// ---------------------------------------------------------------------------
// Kernel 0: RoPE cos/sin tables  [S][32] each, fp64-accurate
// ---------------------------------------------------------------------------
__global__ void freq_kernel(float* __restrict__ ctab, float* __restrict__ stab) {
    int idx = blockIdx.x * blockDim.x + threadIdx.x;   // 0..65535
    int s = idx >> 5;
    int i = idx & 31;
    double f = (double)s * exp(-(double)i * 0.28782313662425573); // ln(1e4)/32
    ctab[idx] = (float)cos(f);
    stab[idx] = (float)sin(f);
}

// ---------------------------------------------------------------------------
// Kernel 1: fp32 -> bf16 hi/lo split into GEMM panel-blocked, PRE-SWIZZLED
// layout (unchanged; GEMM inputs stay 3-term bf16 for fp32-grade accuracy).
// ---------------------------------------------------------------------------
__global__ __launch_bounds__(256) void split_kernel(
    const float* __restrict__ x, const float* __restrict__ wq,
    const float* __restrict__ wp,
    unsigned short* __restrict__ xs, unsigned short* __restrict__ wqs,
    unsigned short* __restrict__ wps)
{
    const int cid  = blockIdx.x * 256 + threadIdx.x;  // 16B output chunk id
    const int panel = cid / 24576;                    // PANEL_SHORTS/8
    const int pos8  = cid % 24576;
    const int step = pos8 >> 10;
    const int rem  = pos8 & 1023;
    const int J    = rem >> 6;
    const int lane = rem & 63;
    const int rowp = J * 8 + (lane >> 3);
    const int lc   = (lane & 7) ^ (rowp & 7);
    const int k    = step * 32 + (lc & 3) * 8;
    const int islo = lc >> 2;
    const float* src; unsigned short* dst; int prow;
    if (panel < PANELS_X) {
        src = x;  dst = xs;  prow = panel;
    } else if (panel < PANELS_X + PANELS_WQ) {
        src = wq; dst = wqs; prow = panel - PANELS_X;
    } else {
        src = wp; dst = wps; prow = panel - PANELS_X - PANELS_WQ;
    }
    const int row = prow * 128 + rowp;
    float4 v0 = *(const float4*)(src + (size_t)row * Cq + k);
    float4 v1 = *(const float4*)(src + (size_t)row * Cq + k + 4);
    float vf[8] = {v0.x, v0.y, v0.z, v0.w, v1.x, v1.y, v1.z, v1.w};
    unsigned short o[8];
    #pragma unroll
    for (int j = 0; j < 8; ++j) {
        unsigned short h = bfbits(vf[j]);
        o[j] = islo ? lobits(vf[j], h) : h;
    }
    *(uint4*)&dst[(size_t)prow * PANEL_SHORTS + (size_t)pos8 * 8] = *(uint4*)o;
}

// ---------------------------------------------------------------------------
// MFMA NT GEMM on panel-blocked pre-swizzled inputs. 128x128 tile, BK=32,
// 4 waves 2x2, 4x4 acc/wave, 3-term split. Staging = identity global_load_lds
// into DOUBLE-BUFFERED LDS: next K-step's loads are issued BEFORE this
// step's ds_read+MFMA, so the single __syncthreads (vmcnt(0) drain) at the
// end of each step finds them complete -> HBM latency hidden (T3-minimum).
// MODE 0: QKV + RoPE epilogue -> SINGLE fp16 images for attention.
// MODE 1: proj + bias -> fp32 [M][768].
// ---------------------------------------------------------------------------
template <int MODE>
__global__ __launch_bounds__(256) void gemm_mfma_kernel(
    const unsigned short* __restrict__ Apr, const unsigned short* __restrict__ Bpr,
    const float* __restrict__ ctab, const float* __restrict__ stab,
    unsigned short* __restrict__ qp, unsigned short* __restrict__ kp,
    unsigned short* __restrict__ vp,
    float* __restrict__ out0, const float* __restrict__ bias)
{
    __shared__ unsigned short sAB[4][128 * 64];   // [0,1]=A dbuf, [2,3]=B dbuf

    const int t    = threadIdx.x;
    const int w    = t >> 6;
    const int lane = t & 63;
    const int ml   = lane & 15;
    const int quad = lane >> 4;
    const int wm   = w >> 1;
    const int wn   = w & 1;

    const int mBase = blockIdx.y * 128;
    const int nBase = blockIdx.x * 128;

    const bool isB = (w >= 2);
    const unsigned short* gpan = (isB ? Bpr : Apr)
        + (size_t)((isB ? nBase : mBase) >> 7) * PANEL_SHORTS;
    const int Jb = (w & 1) * 8;
    unsigned short* sMine = sAB[0] + (isB ? 2 * 8192 : 0);

    // stage K-step `ks` into buffer `buf` (this wave's 8KB half of A or B)
    auto stage = [&](int buf, int ks) {
        const unsigned short* gt = gpan + ks * 8192;
        unsigned short* sd = sMine + buf * 8192;
        #pragma unroll
        for (int j = 0; j < 8; ++j)
            gld_lds16(gt + (Jb + j) * 512 + lane * 8, sd + (Jb + j) * 512);
    };

    stage(0, 0);                 // prologue: buffer 0 in flight

    f32x4 acc[4][4];
    #pragma unroll
    for (int mi = 0; mi < 4; ++mi)
        #pragma unroll
        for (int ni = 0; ni < 4; ++ni)
            acc[mi][ni] = (f32x4){0.f, 0.f, 0.f, 0.f};

    __syncthreads();             // buffer 0 complete

    for (int ks = 0; ks < 24; ++ks) {
        const int cur = ks & 1;
        if (ks + 1 < 24) stage(cur ^ 1, ks + 1);   // prefetch next tile
        const unsigned short* sA = sAB[0] + cur * 8192;
        const unsigned short* sB = sAB[0] + (2 + cur) * 8192;

        bfv8 aFh[4], aFl[4], bFh[4], bFl[4];
        #pragma unroll
        for (int mi = 0; mi < 4; ++mi) {
            const int row = wm * 64 + mi * 16 + ml;
            aFh[mi] = *(const bfv8*)&sA[row * 64 + ((quad ^ (row & 7)) << 3)];
            aFl[mi] = *(const bfv8*)&sA[row * 64 + (((4 + quad) ^ (row & 7)) << 3)];
        }
        #pragma unroll
        for (int ni = 0; ni < 4; ++ni) {
            const int row = wn * 64 + ni * 16 + ml;
            bFh[ni] = *(const bfv8*)&sB[row * 64 + ((quad ^ (row & 7)) << 3)];
            bFl[ni] = *(const bfv8*)&sB[row * 64 + (((4 + quad) ^ (row & 7)) << 3)];
        }
        #pragma unroll
        for (int mi = 0; mi < 4; ++mi)
            #pragma unroll
            for (int ni = 0; ni < 4; ++ni) {
                acc[mi][ni] = MFMA16(aFh[mi], bFh[ni], acc[mi][ni]);
                acc[mi][ni] = MFMA16(aFl[mi], bFh[ni], acc[mi][ni]);
                acc[mi][ni] = MFMA16(aFh[mi], bFl[ni], acc[mi][ni]);
            }
        __syncthreads();         // drains vmcnt(0): next buffer ready,
                                 // and all reads of cur done before restage
    }

    // ---- epilogue (C-layout: row = quad*4 + r, col = ml) ----
    if (MODE == 0) {
        const int which = nBase / Cq;   // 0=q 1=k 2=v
        #pragma unroll
        for (int mi = 0; mi < 4; ++mi) {
            const int gm = mBase + wm * 64 + mi * 16 + quad * 4;  // + r
            const int bb = gm >> 11;
            const int s0 = gm & 2047;
            #pragma unroll
            for (int ni = 0; ni < 4; ++ni) {
                const int gn = nBase + wn * 64 + ni * 16 + ml;
                const int c  = gn - which * Cq;
                const int hh = c >> 6;
                const int dd = c & 63;
                const size_t hb = (size_t)(bb * Hq + hh);
                if (which < 2) {
                    #pragma unroll
                    for (int r = 0; r < 4; ++r) {
                        float val = acc[mi][ni][r];
                        float pv  = __shfl_xor(val, 1, 64);   // d-pair partner
                        const int fi = (s0 + r) * 32 + (dd >> 1);
                        float c0 = ctab[fi], sn = stab[fi];
                        float o = (dd & 1) ? (val * c0 + pv * sn)
                                           : (val * c0 - pv * sn);
                        if (which == 0) {
                            o *= SCALEQ;                      // 1/8 * log2(e)
                            qp[(hb * Sq + s0 + r) * 64 + dd] = f16bits(o);
                        } else {
                            const int ss = s0 + r, rr = ss & 63, kt2 = ss >> 6;
                            kp[(hb * 32 + kt2) * 4096 + rr * 64
                               + (((dd >> 3) ^ (rr & 7)) << 3) + (dd & 7)] = f16bits(o);
                        }
                    }
                } else {
                    // V tile image: row = d, key chunks swizzled by (d&7)
                    unsigned short hv[4];
                    #pragma unroll
                    for (int r = 0; r < 4; ++r)
                        hv[r] = f16bits(acc[mi][ni][r]);
                    const int kt2 = s0 >> 6;
                    *(ushort4*)&vp[(hb * 32 + kt2) * 4096 + dd * 64
                        + ((((s0 & 63) >> 3) ^ (dd & 7)) << 3) + (s0 & 7)]
                        = *(ushort4*)hv;
                }
            }
        }
    } else {
        #pragma unroll
        for (int mi = 0; mi < 4; ++mi) {
            const int gm = mBase + wm * 64 + mi * 16 + quad * 4;
            #pragma unroll
            for (int ni = 0; ni < 4; ++ni) {
                const int gn = nBase + wn * 64 + ni * 16 + ml;
                const float bz = bias[gn];
                #pragma unroll
                for (int r = 0; r < 4; ++r)
                    out0[(size_t)(gm + r) * Cq + gn] = acc[mi][ni][r] + bz;
            }
        }
    }
}

// ---------------------------------------------------------------------------
// Kernel 2: fp16 single-term MFMA flash attention, SWAPPED operands,
// DOUBLE-BUFFERED K/V staging (prefetch kt+1 before compute of kt; single
// __syncthreads per tile drains vmcnt(0) after compute -> latency hidden).
// Grid 768 = 32 qt x 24 bh (XCD = bh%8).
// S^T = mfma(K, Q): lane owns ONE q-column (q = ml); keys = ng*16+quad*4+r.
// Softmax in log2 domain: in-lane max/sum + shfl_xor(16/32); defer-max skip.
// P -> fp16 via v_cvt_pkrtz, transposed through tiny stride-72 LDS buffer
// (uint TBAA family both sides so same-wave round-trip can't reorder).
// O^T = mfma(V^T, P^T); epilogue transposes via LDS (reusing K/V space).
// LDS layout: [0,4K)=K buf0 [4K,8K)=K buf1 [8K,12K)=V buf0 [12K,16K)=V buf1
// [16K, 16K+9K)=pbuf. Buffer bases computed arithmetically (no LDS pointer
// arrays -> avoids addrspacecast static-init codegen error).
// ---------------------------------------------------------------------------
__global__ __launch_bounds__(256, 3) void attn_mfma_kernel(
    const unsigned short* __restrict__ qp, const unsigned short* __restrict__ kp,
    const unsigned short* __restrict__ vp, unsigned short* __restrict__ attns)
{
    __shared__ __align__(16) unsigned short smem[20992];
    unsigned short* pb = smem + 16384;      // [64 q-rows][72] fp16 P (stride 72)

    const int t    = threadIdx.x;
    const int w    = t >> 6;
    const int lane = t & 63;
    const int ml   = lane & 15;
    const int quad = lane >> 4;
    const int bi   = blockIdx.x;
    const int bh   = bi % 24;               // XCD = bh % 8
    const int qt   = bi / 24;               // 0..31

    // staging: waves 0,1 -> K; waves 2,3 -> V; 4KB (4 chunks) per wave
    const bool isV = (w >= 2);
    const unsigned short* gsrc = isV ? vp : kp;
    const int Jb = (w & 1) * 4;
    const size_t gb = (size_t)bh * 131072;  // 32 tiles x 4096 shorts
    unsigned short* sMine = smem + (isV ? 8192 : 0);

    auto stage = [&](int buf, int kt) {
        const unsigned short* gt = gsrc + gb + (size_t)kt * 4096;
        unsigned short* sd = sMine + buf * 4096;
        #pragma unroll
        for (int j = 0; j < 4; ++j)
            gld_lds16(gt + (Jb + j) * 512 + lane * 8, sd + (Jb + j) * 512);
    };

    stage(0, 0);                            // prologue: tile 0 in flight

    // ---- Q B-frag (fp16), q-row = qt*64 + w*16 + ml, col(ml) <-> q ----
    const size_t qrow = ((size_t)bh * Sq + qt * 64 + w * 16 + ml) * 64;
    f16x8 bQ[2];
    bQ[0] = *(const f16x8*)(qp + qrow + quad * 8);
    bQ[1] = *(const f16x8*)(qp + qrow + 32 + quad * 8);

    float m_st = -INFINITY, l_st = 0.f;
    f32x4 O[4];
    #pragma unroll
    for (int ng = 0; ng < 4; ++ng) O[ng] = (f32x4){0.f, 0.f, 0.f, 0.f};

    unsigned short* pbl = pb + (w * 16 + ml) * 72;   // this lane's q-row

    __syncthreads();                        // tile 0 complete

    for (int kt = 0; kt < 32; ++kt) {
        const int cur = kt & 1;
        if (kt + 1 < 32) stage(cur ^ 1, kt + 1);     // prefetch next tile
        const unsigned short* k_s = smem + cur * 4096;
        const unsigned short* v_s = smem + 8192 + cur * 4096;

        // ---- S^T = K x Q (keys x q), 1-term fp16, log2 domain ----
        f32x4 S[4];
        #pragma unroll
        for (int ng = 0; ng < 4; ++ng) {
            const int row = ng * 16 + ml;            // key row (A supply)
            f32x4 acc = (f32x4){0.f, 0.f, 0.f, 0.f};
            #pragma unroll
            for (int ks = 0; ks < 2; ++ks) {
                f16x8 aK = *(const f16x8*)
                    &k_s[row * 64 + (((ks * 4 + quad) ^ (row & 7)) << 3)];
                acc = MFMA16F(aK, bQ[ks], acc);
            }
            S[ng] = acc;
        }

        // ---- online softmax for q = ml: 16 in-lane keys + cross-quad ----
        float a0 = fmaxf(fmaxf(S[0][0], S[0][1]), fmaxf(S[0][2], S[0][3]));
        float a1 = fmaxf(fmaxf(S[1][0], S[1][1]), fmaxf(S[1][2], S[1][3]));
        float a2 = fmaxf(fmaxf(S[2][0], S[2][1]), fmaxf(S[2][2], S[2][3]));
        float a3 = fmaxf(fmaxf(S[3][0], S[3][1]), fmaxf(S[3][2], S[3][3]));
        float mx = fmaxf(fmaxf(a0, a1), fmaxf(a2, a3));
        mx = fmaxf(mx, __shfl_xor(mx, 16, 64));
        mx = fmaxf(mx, __shfl_xor(mx, 32, 64));
        // defer-max: rescale only if tile max outgrew running max by >11 (log2)
        if (__any(mx > m_st + 11.f)) {
            float nm = fmaxf(m_st, mx);
            float al = exp2f(m_st - nm);
            #pragma unroll
            for (int ng = 0; ng < 4; ++ng) O[ng] = O[ng] * al;
            l_st *= al;
            m_st = nm;
        }

        // ---- p = exp2(S - m) -> fp16 pack -> pbuf row (keys in order) ----
        float ps = 0.f;
        #pragma unroll
        for (int ng = 0; ng < 4; ++ng) {
            float p0 = exp2f(S[ng][0] - m_st);
            float p1 = exp2f(S[ng][1] - m_st);
            float p2 = exp2f(S[ng][2] - m_st);
            float p3 = exp2f(S[ng][3] - m_st);
            ps += (p0 + p1) + (p2 + p3);
            uint2 u;
            u.x = pk16(p0, p1);
            u.y = pk16(p2, p3);
            *(uint2*)&pbl[ng * 16 + quad * 4] = u;   // keys ng*16+quad*4..+3
        }
        ps += __shfl_xor(ps, 16, 64);
        ps += __shfl_xor(ps, 32, 64);
        l_st += ps;

        // ---- O^T += V^T x P^T ----
        #pragma unroll
        for (int ks = 0; ks < 2; ++ks) {
            uint4 pu = *(const uint4*)&pbl[ks * 32 + quad * 8];
            f16x8 bP = __builtin_bit_cast(f16x8, pu);
            #pragma unroll
            for (int ngd = 0; ngd < 4; ++ngd) {
                const int row = ngd * 16 + ml;       // d row (A supply)
                f16x8 aV = *(const f16x8*)
                    &v_s[row * 64 + (((ks * 4 + quad) ^ (row & 7)) << 3)];
                O[ngd] = MFMA16F(aV, bP, O[ngd]);
            }
        }
        __syncthreads();        // next tile staged; all reads of cur done
    }

    // ---- epilogue: O^T/l -> LDS transpose -> panel-blocked hi/lo image ----
    float* obuf = (float*)smem;              // [64 q-rows][68] f32 (reuse K/V)
    {
        const float il = 1.0f / l_st;
        float* obl = obuf + (w * 16 + ml) * 68;
        #pragma unroll
        for (int ngd = 0; ngd < 4; ++ngd) {
            f32x4 ov = O[ngd] * il;          // d = ngd*16 + quad*4 + r
            *(f32x4*)&obl[ngd * 16 + quad * 4] = ov;
        }
    }
    __syncthreads();
    const int bb = bh / Hq, hh = bh % Hq;
    #pragma unroll
    for (int r = 0; r < 4; ++r) {
        const int srow = qt * 64 + w * 16 + quad * 4 + r;
        const int mrow = bb * 2048 + srow;
        const int panel = mrow >> 7, r128 = mrow & 127;
        const size_t rbase = (size_t)panel * PANEL_SHORTS
                           + (r128 >> 3) * 512 + (r128 & 7) * 64;
        #pragma unroll
        for (int ng = 0; ng < 4; ++ng) {
            const int k = hh * 64 + ng * 16 + ml;
            float o = obuf[(w * 16 + quad * 4 + r) * 68 + ng * 16 + ml];
            unsigned short h0 = bfbits(o);
            unsigned short l0 = lobits(o, h0);
            const int step = k >> 5;
            const int lch  = (k & 31) >> 3;
            const size_t sb = rbase + (size_t)step * 8192;
            attns[sb + ((lch ^ (r128 & 7)) << 3)       + (k & 7)] = h0;
            attns[sb + (((4 + lch) ^ (r128 & 7)) << 3) + (k & 7)] = l0;
        }
    }
}

// ---------------------------------------------------------------------------
extern "C" void kernel_launch(void* const* d_in, const int* in_sizes, int n_in,
                              void* d_out, int out_size, void* d_ws, size_t ws_size,
                              hipStream_t stream) {
    const float* x     = (const float*)d_in[0];
    const float* Wqkv  = (const float*)d_in[1];
    const float* Wproj = (const float*)d_in[2];
    const float* bproj = (const float*)d_in[3];
    float* out = (float*)d_out;

    char* p = (char*)d_ws;
    unsigned short* xs    = (unsigned short*)p; p += (size_t)PANELS_X  * PANEL_SHORTS * 2;
    unsigned short* wqs   = (unsigned short*)p; p += (size_t)PANELS_WQ * PANEL_SHORTS * 2;
    unsigned short* wps   = (unsigned short*)p; p += (size_t)PANELS_WP * PANEL_SHORTS * 2;
    unsigned short* qp    = (unsigned short*)p; p += (size_t)24 * Sq * 64 * 2;      // fp16
    unsigned short* kp    = (unsigned short*)p; p += (size_t)24 * 131072 * 2;       // fp16
    unsigned short* vp    = (unsigned short*)p; p += (size_t)24 * 131072 * 2;       // fp16
    unsigned short* attns = (unsigned short*)p; p += (size_t)PANELS_X * PANEL_SHORTS * 2;
    float* ctab = (float*)p; p += (size_t)Sq * 32 * 4;
    float* stab = (float*)p; p += (size_t)Sq * 32 * 4;

    freq_kernel<<<256, 256, 0, stream>>>(ctab, stab);
    split_kernel<<<(PANELS_X + PANELS_WQ + PANELS_WP) * 24576 / 256, 256, 0, stream>>>(
        x, Wqkv, Wproj, xs, wqs, wps);
    gemm_mfma_kernel<0><<<dim3(18, 32), 256, 0, stream>>>(
        xs, wqs, ctab, stab, qp, kp, vp, nullptr, nullptr);
    attn_mfma_kernel<<<dim3(32 * 24), 256, 0, stream>>>(qp, kp, vp, attns);
    gemm_mfma_kernel<1><<<dim3(6, 32), 256, 0, stream>>>(
        attns, wps, ctab, stab, nullptr, nullptr, nullptr, out, bproj);
}

// Round 6
// 195.756 us; speedup vs baseline: 1.4911x; 1.1439x over previous
//
#include <hip/hip_runtime.h>
#include <math.h>

// Problem constants
#define Bq 2
#define Sq 2048
#define Cq 768
#define Hq 12
#define Dq 64

// fp16 single panels: 12 steps x 8192 shorts (128 rows x 64 k fp16, swizzled)
#define PANEL_SHORTS 98304
#define PANELS_X  32
#define PANELS_WQ 18
#define PANELS_WP 6

typedef _Float16 f16x8 __attribute__((ext_vector_type(8)));
typedef __fp16 fp16v2 __attribute__((ext_vector_type(2)));   // cvt_pkrtz result type
typedef float f32x4 __attribute__((ext_vector_type(4)));
#define MFMA16F(a, b, c) __builtin_amdgcn_mfma_f32_16x16x32_f16(a, b, c, 0, 0, 0)

// fold head-scale 1/8 and log2(e) into q so attention runs in log2 domain
#define SCALEQ 0.18033688011112042f

static __device__ inline unsigned short f16bits(float x) {
    _Float16 h = (_Float16)x;
    return __builtin_bit_cast(unsigned short, h);
}
static __device__ inline unsigned int pk16(float a, float b) {
    fp16v2 h = __builtin_amdgcn_cvt_pkrtz(a, b);
    return __builtin_bit_cast(unsigned int, h);
}

// async 16B global->LDS copy; lds dest is wave-uniform base (+lane*16 by HW)
static __device__ inline void gld_lds16(const unsigned short* g, unsigned short* l) {
    __builtin_amdgcn_global_load_lds(
        (const __attribute__((address_space(1))) unsigned int*)g,
        (__attribute__((address_space(3))) unsigned int*)l, 16, 0, 0);
}

// ---------------------------------------------------------------------------
// Kernel 0: RoPE cos/sin tables  [S][32] each, fp64-accurate
// ---------------------------------------------------------------------------
__global__ void freq_kernel(float* __restrict__ ctab, float* __restrict__ stab) {
    int idx = blockIdx.x * blockDim.x + threadIdx.x;   // 0..65535
    int s = idx >> 5;
    int i = idx & 31;
    double f = (double)s * exp(-(double)i * 0.28782313662425573); // ln(1e4)/32
    ctab[idx] = (float)cos(f);
    stab[idx] = (float)sin(f);
}

// ---------------------------------------------------------------------------
// Kernel 1: fp32 -> fp16 single into GEMM panel-blocked, PRE-SWIZZLED layout.
// Panel = 128 rows; per BK=64 step a 16 KB block stored in the exact LDS
// image the GEMM DMAs: pos = J*512 + lane*8, row = J*8+(lane>>3),
// phys chunk pc = lane&7 holds logical chunk lc = pc ^ (row&7), k = step*64
// + lc*8. GEMM DMA is an identity copy; ds_read_b128 frags conflict-free.
// ---------------------------------------------------------------------------
__global__ __launch_bounds__(256) void split_kernel(
    const float* __restrict__ x, const float* __restrict__ wq,
    const float* __restrict__ wp,
    unsigned short* __restrict__ xs, unsigned short* __restrict__ wqs,
    unsigned short* __restrict__ wps)
{
    const int cid  = blockIdx.x * 256 + threadIdx.x;  // 16B output chunk id
    const int panel = cid / 12288;                    // PANEL_SHORTS/8
    const int pos8  = cid % 12288;
    const int step = pos8 >> 10;                      // 1024 chunks per step
    const int rem  = pos8 & 1023;
    const int J    = rem >> 6;
    const int lane = rem & 63;
    const int rowp = J * 8 + (lane >> 3);
    const int lc   = (lane & 7) ^ (rowp & 7);
    const int k    = step * 64 + lc * 8;
    const float* src; unsigned short* dst; int prow;
    if (panel < PANELS_X) {
        src = x;  dst = xs;  prow = panel;
    } else if (panel < PANELS_X + PANELS_WQ) {
        src = wq; dst = wqs; prow = panel - PANELS_X;
    } else {
        src = wp; dst = wps; prow = panel - PANELS_X - PANELS_WQ;
    }
    const int row = prow * 128 + rowp;
    float4 v0 = *(const float4*)(src + (size_t)row * Cq + k);
    float4 v1 = *(const float4*)(src + (size_t)row * Cq + k + 4);
    unsigned short o[8] = { f16bits(v0.x), f16bits(v0.y), f16bits(v0.z),
                            f16bits(v0.w), f16bits(v1.x), f16bits(v1.y),
                            f16bits(v1.z), f16bits(v1.w) };
    *(uint4*)&dst[(size_t)prow * PANEL_SHORTS + (size_t)pos8 * 8] = *(uint4*)o;
}

// ---------------------------------------------------------------------------
// MFMA NT GEMM on panel-blocked pre-swizzled fp16 panels. 128x128 tile,
// BK=64, 12 K-steps, 4 waves 2x2, 4x4 acc/wave, SINGLE-TERM fp16
// (3x less MFMA, 2x less staging than the bf16 3-term version; round-5
// showed explicit dbuf hurts -> back to 2-barrier single 32KB buffer).
// MODE 0: QKV + RoPE epilogue -> fp16 images for attention:
//   q -> [bh][s][64] fp16, pre-scaled by 0.125*log2e
//   k -> blocked tile image [bh][kt][key(64) x d-chunks swz] fp16
//   v -> blocked tile image [bh][kt][d(64) x key-chunks swz] fp16
// MODE 1: proj + bias -> fp32 [M][768].
// ---------------------------------------------------------------------------
template <int MODE>
__global__ __launch_bounds__(256) void gemm_mfma_kernel(
    const unsigned short* __restrict__ Apr, const unsigned short* __restrict__ Bpr,
    const float* __restrict__ ctab, const float* __restrict__ stab,
    unsigned short* __restrict__ qp, unsigned short* __restrict__ kp,
    unsigned short* __restrict__ vp,
    float* __restrict__ out0, const float* __restrict__ bias)
{
    __shared__ unsigned short sA[128 * 64];   // 16KB: 128 rows x 64 k fp16
    __shared__ unsigned short sB[128 * 64];

    const int t    = threadIdx.x;
    const int w    = t >> 6;
    const int lane = t & 63;
    const int ml   = lane & 15;
    const int quad = lane >> 4;
    const int wm   = w >> 1;
    const int wn   = w & 1;

    const int mBase = blockIdx.y * 128;
    const int nBase = blockIdx.x * 128;

    // staging role: waves 0,1 -> sA; waves 2,3 -> sB; wl picks 8KB half
    const bool isB = (w >= 2);
    const unsigned short* gpan = (isB ? Bpr : Apr)
        + (size_t)((isB ? nBase : mBase) >> 7) * PANEL_SHORTS;
    unsigned short* sdst = isB ? sB : sA;
    const int Jb = (w & 1) * 8;

    f32x4 acc[4][4];
    #pragma unroll
    for (int mi = 0; mi < 4; ++mi)
        #pragma unroll
        for (int ni = 0; ni < 4; ++ni)
            acc[mi][ni] = (f32x4){0.f, 0.f, 0.f, 0.f};

    for (int k0 = 0; k0 < 12; ++k0) {
        const unsigned short* gt = gpan + k0 * 8192;
        __syncthreads();
        #pragma unroll
        for (int j = 0; j < 8; ++j)
            gld_lds16(gt + (Jb + j) * 512 + lane * 8, sdst + (Jb + j) * 512);
        __syncthreads();

        f16x8 aF[4][2], bF[4][2];
        #pragma unroll
        for (int mi = 0; mi < 4; ++mi) {
            const int row = wm * 64 + mi * 16 + ml;
            #pragma unroll
            for (int ks = 0; ks < 2; ++ks)
                aF[mi][ks] = *(const f16x8*)
                    &sA[row * 64 + (((ks * 4 + quad) ^ (row & 7)) << 3)];
        }
        #pragma unroll
        for (int ni = 0; ni < 4; ++ni) {
            const int row = wn * 64 + ni * 16 + ml;
            #pragma unroll
            for (int ks = 0; ks < 2; ++ks)
                bF[ni][ks] = *(const f16x8*)
                    &sB[row * 64 + (((ks * 4 + quad) ^ (row & 7)) << 3)];
        }
        #pragma unroll
        for (int mi = 0; mi < 4; ++mi)
            #pragma unroll
            for (int ni = 0; ni < 4; ++ni) {
                acc[mi][ni] = MFMA16F(aF[mi][0], bF[ni][0], acc[mi][ni]);
                acc[mi][ni] = MFMA16F(aF[mi][1], bF[ni][1], acc[mi][ni]);
            }
    }

    // ---- epilogue (C-layout: row = quad*4 + r, col = ml) ----
    if (MODE == 0) {
        const int which = nBase / Cq;   // 0=q 1=k 2=v
        #pragma unroll
        for (int mi = 0; mi < 4; ++mi) {
            const int gm = mBase + wm * 64 + mi * 16 + quad * 4;  // + r
            const int bb = gm >> 11;
            const int s0 = gm & 2047;
            #pragma unroll
            for (int ni = 0; ni < 4; ++ni) {
                const int gn = nBase + wn * 64 + ni * 16 + ml;
                const int c  = gn - which * Cq;
                const int hh = c >> 6;
                const int dd = c & 63;
                const size_t hb = (size_t)(bb * Hq + hh);
                if (which < 2) {
                    #pragma unroll
                    for (int r = 0; r < 4; ++r) {
                        float val = acc[mi][ni][r];
                        float pv  = __shfl_xor(val, 1, 64);   // d-pair partner
                        const int fi = (s0 + r) * 32 + (dd >> 1);
                        float c0 = ctab[fi], sn = stab[fi];
                        float o = (dd & 1) ? (val * c0 + pv * sn)
                                           : (val * c0 - pv * sn);
                        if (which == 0) {
                            o *= SCALEQ;                      // 1/8 * log2(e)
                            qp[(hb * Sq + s0 + r) * 64 + dd] = f16bits(o);
                        } else {
                            const int ss = s0 + r, rr = ss & 63, kt2 = ss >> 6;
                            kp[(hb * 32 + kt2) * 4096 + rr * 64
                               + (((dd >> 3) ^ (rr & 7)) << 3) + (dd & 7)] = f16bits(o);
                        }
                    }
                } else {
                    // V tile image: row = d, key chunks swizzled by (d&7)
                    unsigned short hv[4];
                    #pragma unroll
                    for (int r = 0; r < 4; ++r)
                        hv[r] = f16bits(acc[mi][ni][r]);
                    const int kt2 = s0 >> 6;
                    *(ushort4*)&vp[(hb * 32 + kt2) * 4096 + dd * 64
                        + ((((s0 & 63) >> 3) ^ (dd & 7)) << 3) + (s0 & 7)]
                        = *(ushort4*)hv;
                }
            }
        }
    } else {
        #pragma unroll
        for (int mi = 0; mi < 4; ++mi) {
            const int gm = mBase + wm * 64 + mi * 16 + quad * 4;
            #pragma unroll
            for (int ni = 0; ni < 4; ++ni) {
                const int gn = nBase + wn * 64 + ni * 16 + ml;
                const float bz = bias[gn];
                #pragma unroll
                for (int r = 0; r < 4; ++r)
                    out0[(size_t)(gm + r) * Cq + gn] = acc[mi][ni][r] + bz;
            }
        }
    }
}

// ---------------------------------------------------------------------------
// Kernel 2: fp16 single-term MFMA flash attention, SWAPPED operands,
// DOUBLE-BUFFERED K/V staging (helped in round 5 -> kept).
// Grid 768 = 32 qt x 24 bh (XCD = bh%8).
// S^T = mfma(K, Q): lane owns ONE q-column (q = ml); keys = ng*16+quad*4+r.
// Softmax in log2 domain: in-lane max/sum + shfl_xor(16/32); defer-max skip.
// P -> fp16 via v_cvt_pkrtz, transposed through tiny stride-72 LDS buffer
// (uint TBAA family both sides so same-wave round-trip can't reorder).
// O^T = mfma(V^T, P^T); epilogue transposes via LDS (reusing K/V space) and
// writes the proj-GEMM fp16 panel image (single term now).
// LDS: [0,4K)=K buf0 [4K,8K)=K buf1 [8K,12K)=V buf0 [12K,16K)=V buf1
// [16K,16K+9K)=pbuf; bases computed arithmetically (no LDS pointer arrays).
// ---------------------------------------------------------------------------
__global__ __launch_bounds__(256, 3) void attn_mfma_kernel(
    const unsigned short* __restrict__ qp, const unsigned short* __restrict__ kp,
    const unsigned short* __restrict__ vp, unsigned short* __restrict__ attns)
{
    __shared__ __align__(16) unsigned short smem[20992];
    unsigned short* pb = smem + 16384;      // [64 q-rows][72] fp16 P (stride 72)

    const int t    = threadIdx.x;
    const int w    = t >> 6;
    const int lane = t & 63;
    const int ml   = lane & 15;
    const int quad = lane >> 4;
    const int bi   = blockIdx.x;
    const int bh   = bi % 24;               // XCD = bh % 8
    const int qt   = bi / 24;               // 0..31

    // staging: waves 0,1 -> K; waves 2,3 -> V; 4KB (4 chunks) per wave
    const bool isV = (w >= 2);
    const unsigned short* gsrc = isV ? vp : kp;
    const int Jb = (w & 1) * 4;
    const size_t gb = (size_t)bh * 131072;  // 32 tiles x 4096 shorts
    unsigned short* sMine = smem + (isV ? 8192 : 0);

    auto stage = [&](int buf, int kt) {
        const unsigned short* gt = gsrc + gb + (size_t)kt * 4096;
        unsigned short* sd = sMine + buf * 4096;
        #pragma unroll
        for (int j = 0; j < 4; ++j)
            gld_lds16(gt + (Jb + j) * 512 + lane * 8, sd + (Jb + j) * 512);
    };

    stage(0, 0);                            // prologue: tile 0 in flight

    // ---- Q B-frag (fp16), q-row = qt*64 + w*16 + ml, col(ml) <-> q ----
    const size_t qrow = ((size_t)bh * Sq + qt * 64 + w * 16 + ml) * 64;
    f16x8 bQ[2];
    bQ[0] = *(const f16x8*)(qp + qrow + quad * 8);
    bQ[1] = *(const f16x8*)(qp + qrow + 32 + quad * 8);

    float m_st = -INFINITY, l_st = 0.f;
    f32x4 O[4];
    #pragma unroll
    for (int ng = 0; ng < 4; ++ng) O[ng] = (f32x4){0.f, 0.f, 0.f, 0.f};

    unsigned short* pbl = pb + (w * 16 + ml) * 72;   // this lane's q-row

    __syncthreads();                        // tile 0 complete

    for (int kt = 0; kt < 32; ++kt) {
        const int cur = kt & 1;
        if (kt + 1 < 32) stage(cur ^ 1, kt + 1);     // prefetch next tile
        const unsigned short* k_s = smem + cur * 4096;
        const unsigned short* v_s = smem + 8192 + cur * 4096;

        // ---- S^T = K x Q (keys x q), 1-term fp16, log2 domain ----
        f32x4 S[4];
        #pragma unroll
        for (int ng = 0; ng < 4; ++ng) {
            const int row = ng * 16 + ml;            // key row (A supply)
            f32x4 acc = (f32x4){0.f, 0.f, 0.f, 0.f};
            #pragma unroll
            for (int ks = 0; ks < 2; ++ks) {
                f16x8 aK = *(const f16x8*)
                    &k_s[row * 64 + (((ks * 4 + quad) ^ (row & 7)) << 3)];
                acc = MFMA16F(aK, bQ[ks], acc);
            }
            S[ng] = acc;
        }

        // ---- online softmax for q = ml: 16 in-lane keys + cross-quad ----
        float a0 = fmaxf(fmaxf(S[0][0], S[0][1]), fmaxf(S[0][2], S[0][3]));
        float a1 = fmaxf(fmaxf(S[1][0], S[1][1]), fmaxf(S[1][2], S[1][3]));
        float a2 = fmaxf(fmaxf(S[2][0], S[2][1]), fmaxf(S[2][2], S[2][3]));
        float a3 = fmaxf(fmaxf(S[3][0], S[3][1]), fmaxf(S[3][2], S[3][3]));
        float mx = fmaxf(fmaxf(a0, a1), fmaxf(a2, a3));
        mx = fmaxf(mx, __shfl_xor(mx, 16, 64));
        mx = fmaxf(mx, __shfl_xor(mx, 32, 64));
        // defer-max: rescale only if tile max outgrew running max by >11 (log2)
        if (__any(mx > m_st + 11.f)) {
            float nm = fmaxf(m_st, mx);
            float al = exp2f(m_st - nm);
            #pragma unroll
            for (int ng = 0; ng < 4; ++ng) O[ng] = O[ng] * al;
            l_st *= al;
            m_st = nm;
        }

        // ---- p = exp2(S - m) -> fp16 pack -> pbuf row (keys in order) ----
        float ps = 0.f;
        #pragma unroll
        for (int ng = 0; ng < 4; ++ng) {
            float p0 = exp2f(S[ng][0] - m_st);
            float p1 = exp2f(S[ng][1] - m_st);
            float p2 = exp2f(S[ng][2] - m_st);
            float p3 = exp2f(S[ng][3] - m_st);
            ps += (p0 + p1) + (p2 + p3);
            uint2 u;
            u.x = pk16(p0, p1);
            u.y = pk16(p2, p3);
            *(uint2*)&pbl[ng * 16 + quad * 4] = u;   // keys ng*16+quad*4..+3
        }
        ps += __shfl_xor(ps, 16, 64);
        ps += __shfl_xor(ps, 32, 64);
        l_st += ps;

        // ---- O^T += V^T x P^T ----
        #pragma unroll
        for (int ks = 0; ks < 2; ++ks) {
            uint4 pu = *(const uint4*)&pbl[ks * 32 + quad * 8];
            f16x8 bP = __builtin_bit_cast(f16x8, pu);
            #pragma unroll
            for (int ngd = 0; ngd < 4; ++ngd) {
                const int row = ngd * 16 + ml;       // d row (A supply)
                f16x8 aV = *(const f16x8*)
                    &v_s[row * 64 + (((ks * 4 + quad) ^ (row & 7)) << 3)];
                O[ngd] = MFMA16F(aV, bP, O[ngd]);
            }
        }
        __syncthreads();        // next tile staged; all reads of cur done
    }

    // ---- epilogue: O^T/l -> LDS transpose -> fp16 panel image ----
    float* obuf = (float*)smem;              // [64 q-rows][68] f32 (reuse K/V)
    {
        const float il = 1.0f / l_st;
        float* obl = obuf + (w * 16 + ml) * 68;
        #pragma unroll
        for (int ngd = 0; ngd < 4; ++ngd) {
            f32x4 ov = O[ngd] * il;          // d = ngd*16 + quad*4 + r
            *(f32x4*)&obl[ngd * 16 + quad * 4] = ov;
        }
    }
    __syncthreads();
    const int bb = bh / Hq, hh = bh % Hq;
    #pragma unroll
    for (int r = 0; r < 4; ++r) {
        const int srow = qt * 64 + w * 16 + quad * 4 + r;
        const int mrow = bb * 2048 + srow;
        const int panel = mrow >> 7, r128 = mrow & 127;
        const size_t rbase = (size_t)panel * PANEL_SHORTS
                           + (r128 >> 3) * 512 + (r128 & 7) * 64;
        #pragma unroll
        for (int ng = 0; ng < 4; ++ng) {
            const int k = hh * 64 + ng * 16 + ml;
            float o = obuf[(w * 16 + quad * 4 + r) * 68 + ng * 16 + ml];
            const int step = k >> 6;                 // BK=64 panel step
            const int lc   = (k & 63) >> 3;
            attns[rbase + (size_t)step * 8192
                  + ((lc ^ (r128 & 7)) << 3) + (k & 7)] = f16bits(o);
        }
    }
}

// ---------------------------------------------------------------------------
extern "C" void kernel_launch(void* const* d_in, const int* in_sizes, int n_in,
                              void* d_out, int out_size, void* d_ws, size_t ws_size,
                              hipStream_t stream) {
    const float* x     = (const float*)d_in[0];
    const float* Wqkv  = (const float*)d_in[1];
    const float* Wproj = (const float*)d_in[2];
    const float* bproj = (const float*)d_in[3];
    float* out = (float*)d_out;

    char* p = (char*)d_ws;
    unsigned short* xs    = (unsigned short*)p; p += (size_t)PANELS_X  * PANEL_SHORTS * 2;
    unsigned short* wqs   = (unsigned short*)p; p += (size_t)PANELS_WQ * PANEL_SHORTS * 2;
    unsigned short* wps   = (unsigned short*)p; p += (size_t)PANELS_WP * PANEL_SHORTS * 2;
    unsigned short* qp    = (unsigned short*)p; p += (size_t)24 * Sq * 64 * 2;      // fp16
    unsigned short* kp    = (unsigned short*)p; p += (size_t)24 * 131072 * 2;       // fp16
    unsigned short* vp    = (unsigned short*)p; p += (size_t)24 * 131072 * 2;       // fp16
    unsigned short* attns = (unsigned short*)p; p += (size_t)PANELS_X * PANEL_SHORTS * 2;
    float* ctab = (float*)p; p += (size_t)Sq * 32 * 4;
    float* stab = (float*)p; p += (size_t)Sq * 32 * 4;

    freq_kernel<<<256, 256, 0, stream>>>(ctab, stab);
    split_kernel<<<(PANELS_X + PANELS_WQ + PANELS_WP) * 12288 / 256, 256, 0, stream>>>(
        x, Wqkv, Wproj, xs, wqs, wps);
    gemm_mfma_kernel<0><<<dim3(18, 32), 256, 0, stream>>>(
        xs, wqs, ctab, stab, qp, kp, vp, nullptr, nullptr);
    attn_mfma_kernel<<<dim3(32 * 24), 256, 0, stream>>>(qp, kp, vp, attns);
    gemm_mfma_kernel<1><<<dim3(6, 32), 256, 0, stream>>>(
        attns, wps, ctab, stab, nullptr, nullptr, nullptr, out, bproj);
}

// Round 8
// 181.721 us; speedup vs baseline: 1.6062x; 1.0772x over previous
//
#include <hip/hip_runtime.h>
#include <math.h>

// Problem constants
#define Bq 2
#define Sq 2048
#define Cq 768
#define Hq 12
#define Dq 64

// fp16 single panels: 12 steps x 8192 shorts (128 rows x 64 k fp16, swizzled)
#define PANEL_SHORTS 98304
#define PANELS_X  32
#define PANELS_WQ 18
#define PANELS_WP 6

typedef _Float16 f16x8 __attribute__((ext_vector_type(8)));
typedef __fp16 fp16v2 __attribute__((ext_vector_type(2)));   // cvt_pkrtz result type
typedef float f32x4 __attribute__((ext_vector_type(4)));
#define MFMA16F(a, b, c) __builtin_amdgcn_mfma_f32_16x16x32_f16(a, b, c, 0, 0, 0)

// fold head-scale 1/8 and log2(e) into q so attention runs in log2 domain
#define SCALEQ 0.18033688011112042f

static __device__ inline unsigned short f16bits(float x) {
    _Float16 h = (_Float16)x;
    return __builtin_bit_cast(unsigned short, h);
}
static __device__ inline unsigned int pk16(float a, float b) {
    fp16v2 h = __builtin_amdgcn_cvt_pkrtz(a, b);
    return __builtin_bit_cast(unsigned int, h);
}

// async 16B global->LDS copy; lds dest is wave-uniform base (+lane*16 by HW)
static __device__ inline void gld_lds16(const unsigned short* g, unsigned short* l) {
    __builtin_amdgcn_global_load_lds(
        (const __attribute__((address_space(1))) unsigned int*)g,
        (__attribute__((address_space(3))) unsigned int*)l, 16, 0, 0);
}

// ---------------------------------------------------------------------------
// Kernel 0: RoPE cos/sin tables  [S][32] each, fp64-accurate
// ---------------------------------------------------------------------------
__global__ void freq_kernel(float* __restrict__ ctab, float* __restrict__ stab) {
    int idx = blockIdx.x * blockDim.x + threadIdx.x;   // 0..65535
    int s = idx >> 5;
    int i = idx & 31;
    double f = (double)s * exp(-(double)i * 0.28782313662425573); // ln(1e4)/32
    ctab[idx] = (float)cos(f);
    stab[idx] = (float)sin(f);
}

// ---------------------------------------------------------------------------
// Kernel 1: fp32 -> fp16 single into GEMM panel-blocked, PRE-SWIZZLED layout.
// Panel = 128 rows; per BK=64 step a 16 KB block stored in the exact LDS
// image the GEMM DMAs: pos = J*512 + lane*8, row = J*8+(lane>>3),
// phys chunk pc = lane&7 holds logical chunk lc = pc ^ (row&7), k = step*64
// + lc*8. GEMM DMA is an identity copy; ds_read_b128 frags conflict-free.
// ---------------------------------------------------------------------------
__global__ __launch_bounds__(256) void split_kernel(
    const float* __restrict__ x, const float* __restrict__ wq,
    const float* __restrict__ wp,
    unsigned short* __restrict__ xs, unsigned short* __restrict__ wqs,
    unsigned short* __restrict__ wps)
{
    const int cid  = blockIdx.x * 256 + threadIdx.x;  // 16B output chunk id
    const int panel = cid / 12288;                    // PANEL_SHORTS/8
    const int pos8  = cid % 12288;
    const int step = pos8 >> 10;                      // 1024 chunks per step
    const int rem  = pos8 & 1023;
    const int J    = rem >> 6;
    const int lane = rem & 63;
    const int rowp = J * 8 + (lane >> 3);
    const int lc   = (lane & 7) ^ (rowp & 7);
    const int k    = step * 64 + lc * 8;
    const float* src; unsigned short* dst; int prow;
    if (panel < PANELS_X) {
        src = x;  dst = xs;  prow = panel;
    } else if (panel < PANELS_X + PANELS_WQ) {
        src = wq; dst = wqs; prow = panel - PANELS_X;
    } else {
        src = wp; dst = wps; prow = panel - PANELS_X - PANELS_WQ;
    }
    const int row = prow * 128 + rowp;
    float4 v0 = *(const float4*)(src + (size_t)row * Cq + k);
    float4 v1 = *(const float4*)(src + (size_t)row * Cq + k + 4);
    unsigned short o[8] = { f16bits(v0.x), f16bits(v0.y), f16bits(v0.z),
                            f16bits(v0.w), f16bits(v1.x), f16bits(v1.y),
                            f16bits(v1.z), f16bits(v1.w) };
    *(uint4*)&dst[(size_t)prow * PANEL_SHORTS + (size_t)pos8 * 8] = *(uint4*)o;
}

// ---------------------------------------------------------------------------
// MFMA NT GEMM on panel-blocked pre-swizzled fp16 panels. BM x BN tile,
// BK=64, 12 K-steps, 4 waves 2x2, single-term fp16, 2-barrier staging.
// BM=64 (vs 128) doubles/quadruples grid -> blocks/CU 2.25->4.5 (MODE0) and
// 0.75->3.0 (MODE1, BN=64): latency-bound kernels get TLP instead of the
// explicit-dbuf that round 5 showed regresses.
// MODE 0: QKV + RoPE epilogue -> fp16 images for attention.
// MODE 1: proj + bias -> fp32 [M][768].
// ---------------------------------------------------------------------------
template <int MODE, int BM, int BN>
__global__ __launch_bounds__(256) void gemm_mfma_kernel(
    const unsigned short* __restrict__ Apr, const unsigned short* __restrict__ Bpr,
    const float* __restrict__ ctab, const float* __restrict__ stab,
    unsigned short* __restrict__ qp, unsigned short* __restrict__ kp,
    unsigned short* __restrict__ vp,
    float* __restrict__ out0, const float* __restrict__ bias)
{
    constexpr int MI  = BM / 32;           // acc tiles per wave (M)
    constexpr int NI  = BN / 32;           // acc tiles per wave (N)
    constexpr int WTM = BM / 2;            // wave tile M
    constexpr int WTN = BN / 2;            // wave tile N
    constexpr int BCH = BN / 8;            // B chunks (1KB) per K-step
    constexpr int ACH = BM / 8;            // A chunks per K-step
    constexpr int CPW = (ACH + BCH) / 4;   // chunks staged per wave

    __shared__ unsigned short sA[BM * 64];
    __shared__ unsigned short sB[BN * 64];

    const int t    = threadIdx.x;
    const int w    = t >> 6;
    const int lane = t & 63;
    const int ml   = lane & 15;
    const int quad = lane >> 4;
    const int wm   = w >> 1;
    const int wn   = w & 1;

    const int mBase = blockIdx.y * BM;
    const int nBase = blockIdx.x * BN;

    const unsigned short* gpanA = Apr + (size_t)(mBase >> 7) * PANEL_SHORTS;
    const unsigned short* gpanB = Bpr + (size_t)(nBase >> 7) * PANEL_SHORTS;
    const int JbA = (mBase & 127) >> 3;    // 0 or 8 (64-row half of panel)
    const int JbB = (nBase & 127) >> 3;

    f32x4 acc[MI][NI];
    #pragma unroll
    for (int mi = 0; mi < MI; ++mi)
        #pragma unroll
        for (int ni = 0; ni < NI; ++ni)
            acc[mi][ni] = (f32x4){0.f, 0.f, 0.f, 0.f};

    for (int k0 = 0; k0 < 12; ++k0) {
        __syncthreads();
        #pragma unroll
        for (int cc = 0; cc < CPW; ++cc) {
            const int c = w * CPW + cc;    // wave-uniform chunk id
            if (c < BCH) {
                gld_lds16(gpanB + k0 * 8192 + (JbB + c) * 512 + lane * 8,
                          sB + c * 512);
            } else {
                const int a = c - BCH;
                gld_lds16(gpanA + k0 * 8192 + (JbA + a) * 512 + lane * 8,
                          sA + a * 512);
            }
        }
        __syncthreads();

        f16x8 aF[MI][2], bF[NI][2];
        #pragma unroll
        for (int mi = 0; mi < MI; ++mi) {
            const int row = wm * WTM + mi * 16 + ml;
            #pragma unroll
            for (int ks = 0; ks < 2; ++ks)
                aF[mi][ks] = *(const f16x8*)
                    &sA[row * 64 + (((ks * 4 + quad) ^ (row & 7)) << 3)];
        }
        #pragma unroll
        for (int ni = 0; ni < NI; ++ni) {
            const int row = wn * WTN + ni * 16 + ml;
            #pragma unroll
            for (int ks = 0; ks < 2; ++ks)
                bF[ni][ks] = *(const f16x8*)
                    &sB[row * 64 + (((ks * 4 + quad) ^ (row & 7)) << 3)];
        }
        #pragma unroll
        for (int mi = 0; mi < MI; ++mi)
            #pragma unroll
            for (int ni = 0; ni < NI; ++ni) {
                acc[mi][ni] = MFMA16F(aF[mi][0], bF[ni][0], acc[mi][ni]);
                acc[mi][ni] = MFMA16F(aF[mi][1], bF[ni][1], acc[mi][ni]);
            }
    }

    // ---- epilogue (C-layout: row = quad*4 + r, col = ml) ----
    if (MODE == 0) {
        const int which = nBase / Cq;   // 0=q 1=k 2=v
        #pragma unroll
        for (int mi = 0; mi < MI; ++mi) {
            const int gm = mBase + wm * WTM + mi * 16 + quad * 4;  // + r
            const int bb = gm >> 11;
            const int s0 = gm & 2047;
            #pragma unroll
            for (int ni = 0; ni < NI; ++ni) {
                const int gn = nBase + wn * WTN + ni * 16 + ml;
                const int c  = gn - which * Cq;
                const int hh = c >> 6;
                const int dd = c & 63;
                const size_t hb = (size_t)(bb * Hq + hh);
                if (which < 2) {
                    #pragma unroll
                    for (int r = 0; r < 4; ++r) {
                        float val = acc[mi][ni][r];
                        float pv  = __shfl_xor(val, 1, 64);   // d-pair partner
                        const int fi = (s0 + r) * 32 + (dd >> 1);
                        float c0 = ctab[fi], sn = stab[fi];
                        float o = (dd & 1) ? (val * c0 + pv * sn)
                                           : (val * c0 - pv * sn);
                        if (which == 0) {
                            o *= SCALEQ;                      // 1/8 * log2(e)
                            qp[(hb * Sq + s0 + r) * 64 + dd] = f16bits(o);
                        } else {
                            const int ss = s0 + r, rr = ss & 63, kt2 = ss >> 6;
                            kp[(hb * 32 + kt2) * 4096 + rr * 64
                               + (((dd >> 3) ^ (rr & 7)) << 3) + (dd & 7)] = f16bits(o);
                        }
                    }
                } else {
                    // V tile image: row = d, key chunks swizzled by (d&7)
                    unsigned short hv[4];
                    #pragma unroll
                    for (int r = 0; r < 4; ++r)
                        hv[r] = f16bits(acc[mi][ni][r]);
                    const int kt2 = s0 >> 6;
                    *(ushort4*)&vp[(hb * 32 + kt2) * 4096 + dd * 64
                        + ((((s0 & 63) >> 3) ^ (dd & 7)) << 3) + (s0 & 7)]
                        = *(ushort4*)hv;
                }
            }
        }
    } else {
        #pragma unroll
        for (int mi = 0; mi < MI; ++mi) {
            const int gm = mBase + wm * WTM + mi * 16 + quad * 4;
            #pragma unroll
            for (int ni = 0; ni < NI; ++ni) {
                const int gn = nBase + wn * WTN + ni * 16 + ml;
                const float bz = bias[gn];
                #pragma unroll
                for (int r = 0; r < 4; ++r)
                    out0[(size_t)(gm + r) * Cq + gn] = acc[mi][ni][r] + bz;
            }
        }
    }
}

// ---------------------------------------------------------------------------
// Kernel 2: fp16 single-term MFMA flash attention, SWAPPED operands,
// DOUBLE-BUFFERED K/V staging. Grid 768 = 32 qt x 24 bh (XCD = bh%8).
// S^T = mfma(K, Q): lane owns ONE q-column (q = ml); keys = ng*16+quad*4+r.
// Softmax in log2 domain: in-lane max/sum + shfl_xor(16/32); defer-max skip.
// P -> fp16 via v_cvt_pkrtz through stride-64 XOR-swizzled pbuf: 16B chunk
// ch at row goes to phys chunk ch^(row&7) -> b128 reads match the proven
// K/V-tile conflict-free structure (uint TBAA family both sides).
// O^T = mfma(V^T, P^T); epilogue transposes via LDS (reusing K/V space) and
// writes the proj-GEMM fp16 panel image.
// LDS: [0,4K)=K buf0 [4K,8K)=K buf1 [8K,12K)=V buf0 [12K,16K)=V buf1
// [16K,20K)=pbuf (shorts); bases computed arithmetically.
// ---------------------------------------------------------------------------
__global__ __launch_bounds__(256, 3) void attn_mfma_kernel(
    const unsigned short* __restrict__ qp, const unsigned short* __restrict__ kp,
    const unsigned short* __restrict__ vp, unsigned short* __restrict__ attns)
{
    __shared__ __align__(16) unsigned short smem[20480];
    unsigned short* pb = smem + 16384;      // [64 q-rows][64] fp16 P, XOR-swz

    const int t    = threadIdx.x;
    const int w    = t >> 6;
    const int lane = t & 63;
    const int ml   = lane & 15;
    const int quad = lane >> 4;
    const int bi   = blockIdx.x;
    const int bh   = bi % 24;               // XCD = bh % 8
    const int qt   = bi / 24;               // 0..31

    // staging: waves 0,1 -> K; waves 2,3 -> V; 4KB (4 chunks) per wave
    const bool isV = (w >= 2);
    const unsigned short* gsrc = isV ? vp : kp;
    const int Jb = (w & 1) * 4;
    const size_t gb = (size_t)bh * 131072;  // 32 tiles x 4096 shorts
    unsigned short* sMine = smem + (isV ? 8192 : 0);

    auto stage = [&](int buf, int kt) {
        const unsigned short* gt = gsrc + gb + (size_t)kt * 4096;
        unsigned short* sd = sMine + buf * 4096;
        #pragma unroll
        for (int j = 0; j < 4; ++j)
            gld_lds16(gt + (Jb + j) * 512 + lane * 8, sd + (Jb + j) * 512);
    };

    stage(0, 0);                            // prologue: tile 0 in flight

    // ---- Q B-frag (fp16), q-row = qt*64 + w*16 + ml, col(ml) <-> q ----
    const size_t qrow = ((size_t)bh * Sq + qt * 64 + w * 16 + ml) * 64;
    f16x8 bQ[2];
    bQ[0] = *(const f16x8*)(qp + qrow + quad * 8);
    bQ[1] = *(const f16x8*)(qp + qrow + 32 + quad * 8);

    float m_st = -INFINITY, l_st = 0.f;
    f32x4 O[4];
    #pragma unroll
    for (int ng = 0; ng < 4; ++ng) O[ng] = (f32x4){0.f, 0.f, 0.f, 0.f};

    unsigned short* pbl = pb + (w * 16 + ml) * 64;   // this lane's q-row
    const int rsw = ml & 7;                          // row swizzle key

    __syncthreads();                        // tile 0 complete

    for (int kt = 0; kt < 32; ++kt) {
        const int cur = kt & 1;
        if (kt + 1 < 32) stage(cur ^ 1, kt + 1);     // prefetch next tile
        const unsigned short* k_s = smem + cur * 4096;
        const unsigned short* v_s = smem + 8192 + cur * 4096;

        // ---- S^T = K x Q (keys x q), 1-term fp16, log2 domain ----
        f32x4 S[4];
        #pragma unroll
        for (int ng = 0; ng < 4; ++ng) {
            const int row = ng * 16 + ml;            // key row (A supply)
            f32x4 acc = (f32x4){0.f, 0.f, 0.f, 0.f};
            #pragma unroll
            for (int ks = 0; ks < 2; ++ks) {
                f16x8 aK = *(const f16x8*)
                    &k_s[row * 64 + (((ks * 4 + quad) ^ (row & 7)) << 3)];
                acc = MFMA16F(aK, bQ[ks], acc);
            }
            S[ng] = acc;
        }

        // ---- online softmax for q = ml: 16 in-lane keys + cross-quad ----
        float a0 = fmaxf(fmaxf(S[0][0], S[0][1]), fmaxf(S[0][2], S[0][3]));
        float a1 = fmaxf(fmaxf(S[1][0], S[1][1]), fmaxf(S[1][2], S[1][3]));
        float a2 = fmaxf(fmaxf(S[2][0], S[2][1]), fmaxf(S[2][2], S[2][3]));
        float a3 = fmaxf(fmaxf(S[3][0], S[3][1]), fmaxf(S[3][2], S[3][3]));
        float mx = fmaxf(fmaxf(a0, a1), fmaxf(a2, a3));
        mx = fmaxf(mx, __shfl_xor(mx, 16, 64));
        mx = fmaxf(mx, __shfl_xor(mx, 32, 64));
        // defer-max: rescale only if tile max outgrew running max by >11 (log2)
        if (__any(mx > m_st + 11.f)) {
            float nm = fmaxf(m_st, mx);
            float al = exp2f(m_st - nm);
            #pragma unroll
            for (int ng = 0; ng < 4; ++ng) O[ng] = O[ng] * al;
            l_st *= al;
            m_st = nm;
        }

        // ---- p = exp2(S - m) -> fp16 pack -> pbuf row (XOR-swz chunks) ----
        float ps = 0.f;
        #pragma unroll
        for (int ng = 0; ng < 4; ++ng) {
            float p0 = exp2f(S[ng][0] - m_st);
            float p1 = exp2f(S[ng][1] - m_st);
            float p2 = exp2f(S[ng][2] - m_st);
            float p3 = exp2f(S[ng][3] - m_st);
            ps += (p0 + p1) + (p2 + p3);
            uint2 u;
            u.x = pk16(p0, p1);
            u.y = pk16(p2, p3);
            const int ch = ng * 2 + (quad >> 1);     // logical 16B chunk
            *(uint2*)&pbl[((ch ^ rsw) << 3) + (quad & 1) * 4] = u;
        }
        ps += __shfl_xor(ps, 16, 64);
        ps += __shfl_xor(ps, 32, 64);
        l_st += ps;

        // ---- O^T += V^T x P^T ----
        #pragma unroll
        for (int ks = 0; ks < 2; ++ks) {
            uint4 pu = *(const uint4*)&pbl[(((ks * 4 + quad) ^ rsw) << 3)];
            f16x8 bP = __builtin_bit_cast(f16x8, pu);
            #pragma unroll
            for (int ngd = 0; ngd < 4; ++ngd) {
                const int row = ngd * 16 + ml;       // d row (A supply)
                f16x8 aV = *(const f16x8*)
                    &v_s[row * 64 + (((ks * 4 + quad) ^ (row & 7)) << 3)];
                O[ngd] = MFMA16F(aV, bP, O[ngd]);
            }
        }
        __syncthreads();        // next tile staged; all reads of cur done
    }

    // ---- epilogue: O^T/l -> LDS transpose -> fp16 panel image ----
    float* obuf = (float*)smem;              // [64 q-rows][68] f32 (reuse K/V)
    {
        const float il = 1.0f / l_st;
        float* obl = obuf + (w * 16 + ml) * 68;
        #pragma unroll
        for (int ngd = 0; ngd < 4; ++ngd) {
            f32x4 ov = O[ngd] * il;          // d = ngd*16 + quad*4 + r
            *(f32x4*)&obl[ngd * 16 + quad * 4] = ov;
        }
    }
    __syncthreads();
    const int bb = bh / Hq, hh = bh % Hq;
    #pragma unroll
    for (int r = 0; r < 4; ++r) {
        const int srow = qt * 64 + w * 16 + quad * 4 + r;
        const int mrow = bb * 2048 + srow;
        const int panel = mrow >> 7, r128 = mrow & 127;
        const size_t rbase = (size_t)panel * PANEL_SHORTS
                           + (r128 >> 3) * 512 + (r128 & 7) * 64;
        #pragma unroll
        for (int ng = 0; ng < 4; ++ng) {
            const int k = hh * 64 + ng * 16 + ml;
            float o = obuf[(w * 16 + quad * 4 + r) * 68 + ng * 16 + ml];
            const int step = k >> 6;                 // BK=64 panel step
            const int lc   = (k & 63) >> 3;
            attns[rbase + (size_t)step * 8192
                  + ((lc ^ (r128 & 7)) << 3) + (k & 7)] = f16bits(o);
        }
    }
}

// ---------------------------------------------------------------------------
extern "C" void kernel_launch(void* const* d_in, const int* in_sizes, int n_in,
                              void* d_out, int out_size, void* d_ws, size_t ws_size,
                              hipStream_t stream) {
    const float* x     = (const float*)d_in[0];
    const float* Wqkv  = (const float*)d_in[1];
    const float* Wproj = (const float*)d_in[2];
    const float* bproj = (const float*)d_in[3];
    float* out = (float*)d_out;

    char* p = (char*)d_ws;
    unsigned short* xs    = (unsigned short*)p; p += (size_t)PANELS_X  * PANEL_SHORTS * 2;
    unsigned short* wqs   = (unsigned short*)p; p += (size_t)PANELS_WQ * PANEL_SHORTS * 2;
    unsigned short* wps   = (unsigned short*)p; p += (size_t)PANELS_WP * PANEL_SHORTS * 2;
    unsigned short* qp    = (unsigned short*)p; p += (size_t)24 * Sq * 64 * 2;      // fp16
    unsigned short* kp    = (unsigned short*)p; p += (size_t)24 * 131072 * 2;       // fp16
    unsigned short* vp    = (unsigned short*)p; p += (size_t)24 * 131072 * 2;       // fp16
    unsigned short* attns = (unsigned short*)p; p += (size_t)PANELS_X * PANEL_SHORTS * 2;
    float* ctab = (float*)p; p += (size_t)Sq * 32 * 4;
    float* stab = (float*)p; p += (size_t)Sq * 32 * 4;

    freq_kernel<<<256, 256, 0, stream>>>(ctab, stab);
    split_kernel<<<(PANELS_X + PANELS_WQ + PANELS_WP) * 12288 / 256, 256, 0, stream>>>(
        x, Wqkv, Wproj, xs, wqs, wps);
    gemm_mfma_kernel<0, 64, 128><<<dim3(18, 64), 256, 0, stream>>>(
        xs, wqs, ctab, stab, qp, kp, vp, nullptr, nullptr);
    attn_mfma_kernel<<<dim3(32 * 24), 256, 0, stream>>>(qp, kp, vp, attns);
    gemm_mfma_kernel<1, 64, 64><<<dim3(12, 64), 256, 0, stream>>>(
        attns, wps, ctab, stab, nullptr, nullptr, nullptr, out, bproj);
}